// Round 9
// baseline (1716.389 us; speedup 1.0000x reference)
//
#include <hip/hip_runtime.h>
#include <hip/hip_bf16.h>

#define RG86_NN 50000
#define RG86_NE 320000
#define RG86_NR 3
#define RG86_DIN 768
#define RG86_HID 256
#define RG86_OUT 64

static __device__ float rg_b2f(unsigned short u) {
  return __uint_as_float(((unsigned int)u) << 16);
}
static __device__ unsigned short rg_f2b(float f) {
  unsigned int u = __float_as_uint(f);
  u += 0x7FFFu + ((u >> 16) & 1u);
  return (unsigned short)(u >> 16);
}

__global__ void RGATModel_86371792322702_kernel() {}

// C[M][N] = A[M][K]*B[K][N] (+bias, opt relu). fp32 in; out fp32 (Cf) or bf16 (Cb).
// 64x64 tile, 256 thr, 1D grid (mblk m-tiles per n-tile).
__global__ void rg_gemm(const float* A, const float* B, const float* bias,
                        float* Cf, unsigned short* Cb,
                        int M, int N, int K, int relu, int mblk) {
  __shared__ float sA[16][68];
  __shared__ float sB[16][68];
  int tid = threadIdx.x;
  int m0 = (blockIdx.x % mblk) * 64, n0 = (blockIdx.x / mblk) * 64;
  int am = tid >> 2, ak = (tid & 3) * 4;
  int bk = tid >> 4, bn = (tid & 15) * 4;
  int tx = tid & 15, ty = tid >> 4;
  float acc[4][4] = {};
  for (int k0 = 0; k0 < K; k0 += 16) {
    float4 av = make_float4(0.f, 0.f, 0.f, 0.f);
    if (m0 + am < M) av = *(const float4*)(A + (size_t)(m0 + am) * K + k0 + ak);
    sA[ak + 0][am] = av.x;
    sA[ak + 1][am] = av.y;
    sA[ak + 2][am] = av.z;
    sA[ak + 3][am] = av.w;
    float4 bv = *(const float4*)(B + (size_t)(k0 + bk) * N + n0 + bn);
    sB[bk][bn + 0] = bv.x;
    sB[bk][bn + 1] = bv.y;
    sB[bk][bn + 2] = bv.z;
    sB[bk][bn + 3] = bv.w;
    __syncthreads();
#pragma unroll
    for (int kk = 0; kk < 16; kk++) {
      float a[4], b[4];
#pragma unroll
      for (int i = 0; i < 4; i++) { a[i] = sA[kk][ty * 4 + i]; b[i] = sB[kk][tx * 4 + i]; }
#pragma unroll
      for (int i = 0; i < 4; i++)
#pragma unroll
        for (int j = 0; j < 4; j++) acc[i][j] += a[i] * b[j];
    }
    __syncthreads();
  }
  for (int i = 0; i < 4; i++) {
    int row = m0 + ty * 4 + i;
    if (row >= M) continue;
    for (int j = 0; j < 4; j++) {
      int col = n0 + tx * 4 + j;
      float v = acc[i][j];
      if (bias) v += bias[col];
      if (relu && v < 0.f) v = 0.f;
      if (Cb) Cb[(size_t)row * N + col] = rg_f2b(v);
      else Cf[(size_t)row * N + col] = v;
    }
  }
}

__global__ void rg_hist(const int* d, int* counts) {
  int e = blockIdx.x * 256 + threadIdx.x;
  if (e < RG86_NE) atomicAdd(&counts[d[e]], 1);
}

// single block; exclusive scan -> rowptr and cursor
__global__ void rg_scan(const int* counts, int* rowptr, int* cursor, int n) {
  __shared__ int buf[256];
  __shared__ int carry;
  if (threadIdx.x == 0) carry = 0;
  __syncthreads();
  for (int base = 0; base < n; base += 256) {
    int i = base + threadIdx.x;
    int v = (i < n) ? counts[i] : 0;
    buf[threadIdx.x] = v;
    __syncthreads();
    for (int off = 1; off < 256; off <<= 1) {
      int t = (threadIdx.x >= off) ? buf[threadIdx.x - off] : 0;
      __syncthreads();
      buf[threadIdx.x] += t;
      __syncthreads();
    }
    if (i < n) { rowptr[i] = carry + buf[threadIdx.x] - v; cursor[i] = rowptr[i]; }
    int total = buf[255];
    __syncthreads();
    if (threadIdx.x == 0) carry += total;
    __syncthreads();
  }
  if (threadIdx.x == 0) rowptr[n] = carry;
}

__global__ void rg_scatter(const int* d, int* cursor, int* perm) {
  int e = blockIdx.x * 256 + threadIdx.x;
  if (e < RG86_NE) perm[atomicAdd(&cursor[d[e]], 1)] = e;
}

// per-(rel,node): qd = xw.q, kd = xw.k ; one wave each. xw bf16, q/k fp32.
__global__ void rg_qk(const unsigned short* xw, const float* q, const float* k,
                      float* qd, float* kd) {
  int lane = threadIdx.x & 63;
  int p = blockIdx.x * 4 + (threadIdx.x >> 6);
  if (p >= RG86_NR * RG86_NN) return;
  const unsigned short* xr = xw + (size_t)p * RG86_HID + lane * 4;
  float qv = 0.f, kv = 0.f;
  for (int j = 0; j < 4; j++) {
    float xv = rg_b2f(xr[j]);
    qv += xv * q[lane * 4 + j];
    kv += xv * k[lane * 4 + j];
  }
  for (int o = 32; o >= 1; o >>= 1) { qv += __shfl_xor(qv, o); kv += __shfl_xor(kv, o); }
  if (lane == 0) { qd[p] = qv; kd[p] = kv; }
}

// wave per node: leaky-relu logits, segment softmax, weighted gather. out fp32.
__global__ void rg_agg(const int* rowptr, const int* perm, const int* src,
                       const int* et, const float* qd, const float* kd,
                       const unsigned short* xw, const float* bias, float* out) {
  int lane = threadIdx.x & 63;
  int node = blockIdx.x * 4 + (threadIdx.x >> 6);
  if (node >= RG86_NN) return;
  int s0 = rowptr[node], s1 = rowptr[node + 1];
  int c0 = lane * 4;
  float a0 = 0.f, a1 = 0.f, a2 = 0.f, a3 = 0.f;
  if (s1 > s0) {
    float q0 = qd[node], q1 = qd[RG86_NN + node], q2 = qd[2 * RG86_NN + node];
    float m = -1e30f;
    for (int i = s0; i < s1; i++) {
      int e = perm[i], t = et[e];
      float al = (t == 0 ? q0 : t == 1 ? q1 : q2) + kd[t * RG86_NN + src[e]];
      al = al > 0.f ? al : 0.2f * al;
      m = fmaxf(m, al);
    }
    float den = 0.f;
    for (int i = s0; i < s1; i++) {
      int e = perm[i], t = et[e];
      float al = (t == 0 ? q0 : t == 1 ? q1 : q2) + kd[t * RG86_NN + src[e]];
      al = al > 0.f ? al : 0.2f * al;
      den += __expf(al - m);
    }
    float inv = 1.f / (den + 1e-16f);
    for (int i = s0; i < s1; i++) {
      int e = perm[i], t = et[e], sv = src[e];
      float al = (t == 0 ? q0 : t == 1 ? q1 : q2) + kd[t * RG86_NN + sv];
      al = al > 0.f ? al : 0.2f * al;
      float w = __expf(al - m) * inv;
      ushort4 xr = *(const ushort4*)(xw + ((size_t)t * RG86_NN + sv) * RG86_HID + c0);
      a0 += w * rg_b2f(xr.x);
      a1 += w * rg_b2f(xr.y);
      a2 += w * rg_b2f(xr.z);
      a3 += w * rg_b2f(xr.w);
    }
  }
  float* op = out + (size_t)node * RG86_HID + c0;
  op[0] = a0 + bias[c0 + 0];
  op[1] = a1 + bias[c0 + 1];
  op[2] = a2 + bias[c0 + 2];
  op[3] = a3 + bias[c0 + 3];
}

__global__ void rg_cls(const float* h4, const float* wc, const float* bc,
                       float* out) {
  int n = blockIdx.x * 256 + threadIdx.x;
  if (n >= RG86_NN) return;
  float a0 = bc[0], a1 = bc[1];
  const float* hr = h4 + (size_t)n * RG86_OUT;
  for (int j = 0; j < RG86_OUT; j++) {
    float h = hr[j];
    a0 += h * wc[j * 2 + 0];
    a1 += h * wc[j * 2 + 1];
  }
  out[n * 2 + 0] = a0;
  out[n * 2 + 1] = a1;
}

extern "C" void kernel_launch(void* const* d_in, const int* in_sizes, int n_in,
                              void* d_out, int out_size, void* d_ws, size_t ws_size,
                              hipStream_t stream) {
  (void)in_sizes; (void)n_in; (void)out_size;
  const float* x = (const float*)d_in[0];
  const int* ei = (const int*)d_in[1];
  const int* etp = (const int*)d_in[2];
  const float* w_in = (const float*)d_in[3];
  const float* b_in = (const float*)d_in[4];
  const float* c1w = (const float*)d_in[5];
  const float* c1q = (const float*)d_in[6];
  const float* c1k = (const float*)d_in[7];
  const float* c1b = (const float*)d_in[8];
  const float* c2w = (const float*)d_in[9];
  const float* c2q = (const float*)d_in[10];
  const float* c2k = (const float*)d_in[11];
  const float* c2b = (const float*)d_in[12];
  const float* w_out = (const float*)d_in[13];
  const float* b_out = (const float*)d_in[14];
  const float* w_cls = (const float*)d_in[15];
  const float* b_cls = (const float*)d_in[16];
  const int* esrc = ei;
  const int* edst = ei + RG86_NE;

  char* base = (char*)d_ws;
  size_t off = 0;
  float* h1 = (float*)(base + off); off += (size_t)RG86_NN * RG86_HID * 4;
  float* h2 = (float*)(base + off); off += (size_t)RG86_NN * RG86_HID * 4;
  float* h4 = (float*)(base + off); off += (size_t)RG86_NN * RG86_OUT * 4;
  unsigned short* xw = (unsigned short*)(base + off);
  off += (size_t)RG86_NR * RG86_NN * RG86_HID * 2;
  float* qd = (float*)(base + off); off += (size_t)RG86_NR * RG86_NN * 4;
  float* kd = (float*)(base + off); off += (size_t)RG86_NR * RG86_NN * 4;
  int* counts = (int*)(base + off); off += (size_t)RG86_NN * 4;
  int* rowptr = (int*)(base + off); off += (size_t)(RG86_NN + 4) * 4;
  int* cursor = (int*)(base + off); off += (size_t)RG86_NN * 4;
  int* perm = (int*)(base + off); off += (size_t)RG86_NE * 4;
  if (off > ws_size) return;  // signature: absmax 0.9492 => ws too small

  int mblk = (RG86_NN + 63) / 64;
  int gh = mblk * (RG86_HID / 64);

  // h1 = relu(x @ w_in + b_in), fp32
  rg_gemm<<<gh, 256, 0, stream>>>(x, w_in, b_in, h1, (unsigned short*)0,
                                  RG86_NN, RG86_HID, RG86_DIN, 1, mblk);

  hipMemsetAsync(counts, 0, (size_t)RG86_NN * 4, stream);
  rg_hist<<<(RG86_NE + 255) / 256, 256, 0, stream>>>(edst, counts);
  rg_scan<<<1, 256, 0, stream>>>(counts, rowptr, cursor, RG86_NN);
  rg_scatter<<<(RG86_NE + 255) / 256, 256, 0, stream>>>(edst, cursor, perm);

  // conv1: xw[r] = h1 @ c1w[r]  (bf16 out), then attention-aggregate -> h2
  for (int r = 0; r < RG86_NR; r++)
    rg_gemm<<<gh, 256, 0, stream>>>(h1, c1w + (size_t)r * RG86_HID * RG86_HID,
                                    (const float*)0, (float*)0,
                                    xw + (size_t)r * RG86_NN * RG86_HID,
                                    RG86_NN, RG86_HID, RG86_HID, 0, mblk);
  rg_qk<<<(RG86_NR * RG86_NN + 3) / 4, 256, 0, stream>>>(xw, c1q, c1k, qd, kd);
  rg_agg<<<(RG86_NN + 3) / 4, 256, 0, stream>>>(rowptr, perm, esrc, etp, qd, kd,
                                                xw, c1b, h2);

  // conv2: h2 -> h1
  for (int r = 0; r < RG86_NR; r++)
    rg_gemm<<<gh, 256, 0, stream>>>(h2, c2w + (size_t)r * RG86_HID * RG86_HID,
                                    (const float*)0, (float*)0,
                                    xw + (size_t)r * RG86_NN * RG86_HID,
                                    RG86_NN, RG86_HID, RG86_HID, 0, mblk);
  rg_qk<<<(RG86_NR * RG86_NN + 3) / 4, 256, 0, stream>>>(xw, c2q, c2k, qd, kd);
  rg_agg<<<(RG86_NN + 3) / 4, 256, 0, stream>>>(rowptr, perm, esrc, etp, qd, kd,
                                                xw, c2b, h1);

  // h4 = relu(h1 @ w_out + b_out), fp32
  rg_gemm<<<mblk, 256, 0, stream>>>(h1, w_out, b_out, h4, (unsigned short*)0,
                                    RG86_NN, RG86_OUT, RG86_HID, 1, mblk);

  // logits = h4 @ w_cls + b_cls
  rg_cls<<<(RG86_NN + 255) / 256, 256, 0, stream>>>(h4, w_cls, b_cls, (float*)d_out);
}

// Round 10
// 1074.251 us; speedup vs baseline: 1.5978x; 1.5978x over previous
//
#include <hip/hip_runtime.h>
#include <hip/hip_bf16.h>

#define RG86_NN 50000
#define RG86_NE 320000
#define RG86_NR 3
#define RG86_DIN 768
#define RG86_HID 256
#define RG86_OUT 64

typedef __bf16 rg_bv8 __attribute__((ext_vector_type(8)));
typedef short rg_sv8 __attribute__((ext_vector_type(8)));
typedef float rg_fv4 __attribute__((ext_vector_type(4)));

static __device__ float rg_b2f(unsigned short u) {
  return __uint_as_float(((unsigned int)u) << 16);
}
static __device__ unsigned short rg_f2b(float f) {
  unsigned int u = __float_as_uint(f);
  u += 0x7FFFu + ((u >> 16) & 1u);
  return (unsigned short)(u >> 16);
}

__global__ void RGATModel_86371792322702_kernel() {}

// fp32 -> bf16 elementwise, 4 per thread (n multiple of 4)
__global__ void rg_cast(const float* in, unsigned short* out, int n) {
  int i = (blockIdx.x * 256 + threadIdx.x) * 4;
  if (i < n) {
    float4 v = *(const float4*)(in + i);
    ushort4 o = make_ushort4(rg_f2b(v.x), rg_f2b(v.y), rg_f2b(v.z), rg_f2b(v.w));
    *(ushort4*)(out + i) = o;
  }
}

// fp32 [rows][cols] -> bf16 [cols][rows]
__global__ void rg_castT(const float* in, unsigned short* out, int rows, int cols) {
  int i = blockIdx.x * 256 + threadIdx.x;
  if (i < rows * cols) {
    int r = i / cols, c = i % cols;
    out[(size_t)c * rows + r] = rg_f2b(in[i]);
  }
}

// MFMA GEMM: C[M][N] = A[M][K] * Bt[N][K]^T (+bias fp32, opt relu), bf16 in/out.
// 64x64 tile, 256 thr (4 waves), K-step 32, 16x16x32 bf16 MFMA.
__global__ void rg_gemm_m(const unsigned short* A, const unsigned short* Bt,
                          const float* bias, unsigned short* C,
                          int M, int N, int K, int relu, int mblk) {
  __shared__ unsigned short sA[64][40];
  __shared__ unsigned short sB[64][40];
  int tid = threadIdx.x;
  int wave = tid >> 6, lane = tid & 63;
  int m0 = (blockIdx.x % mblk) * 64, n0 = (blockIdx.x / mblk) * 64;
  int lr = tid >> 2, lk = (tid & 3) * 8;
  int frow = lane & 15, fk = (lane >> 4) * 8;
  rg_fv4 acc[4] = {};
  for (int k0 = 0; k0 < K; k0 += 32) {
    rg_sv8 av = {};
    if (m0 + lr < M) av = *(const rg_sv8*)(A + (size_t)(m0 + lr) * K + k0 + lk);
    *(rg_sv8*)&sA[lr][lk] = av;
    rg_sv8 bv = *(const rg_sv8*)(Bt + (size_t)(n0 + lr) * K + k0 + lk);
    *(rg_sv8*)&sB[lr][lk] = bv;
    __syncthreads();
    rg_bv8 a = *(const rg_bv8*)&sA[wave * 16 + frow][fk];
#pragma unroll
    for (int t = 0; t < 4; t++) {
      rg_bv8 b = *(const rg_bv8*)&sB[t * 16 + frow][fk];
      acc[t] = __builtin_amdgcn_mfma_f32_16x16x32_bf16(a, b, acc[t], 0, 0, 0);
    }
    __syncthreads();
  }
  int orow = m0 + wave * 16 + (lane >> 4) * 4;
  int ocol = n0 + (lane & 15);
  for (int t = 0; t < 4; t++) {
    int col = ocol + t * 16;
    float bv = bias ? bias[col] : 0.f;
    for (int r = 0; r < 4; r++) {
      int row = orow + r;
      if (row < M) {
        float v = acc[t][r] + bv;
        if (relu && v < 0.f) v = 0.f;
        C[(size_t)row * N + col] = rg_f2b(v);
      }
    }
  }
}

__global__ void rg_hist(const int* d, int* counts) {
  int e = blockIdx.x * 256 + threadIdx.x;
  if (e < RG86_NE) atomicAdd(&counts[d[e]], 1);
}

__global__ void rg_scan(const int* counts, int* rowptr, int* cursor, int n) {
  __shared__ int buf[256];
  __shared__ int carry;
  if (threadIdx.x == 0) carry = 0;
  __syncthreads();
  for (int base = 0; base < n; base += 256) {
    int i = base + threadIdx.x;
    int v = (i < n) ? counts[i] : 0;
    buf[threadIdx.x] = v;
    __syncthreads();
    for (int off = 1; off < 256; off <<= 1) {
      int t = (threadIdx.x >= off) ? buf[threadIdx.x - off] : 0;
      __syncthreads();
      buf[threadIdx.x] += t;
      __syncthreads();
    }
    if (i < n) { rowptr[i] = carry + buf[threadIdx.x] - v; cursor[i] = rowptr[i]; }
    int total = buf[255];
    __syncthreads();
    if (threadIdx.x == 0) carry += total;
    __syncthreads();
  }
  if (threadIdx.x == 0) rowptr[n] = carry;
}

__global__ void rg_scatter(const int* d, int* cursor, int* perm) {
  int e = blockIdx.x * 256 + threadIdx.x;
  if (e < RG86_NE) perm[atomicAdd(&cursor[d[e]], 1)] = e;
}

// per-(rel,node): qd = xw.q, kd = xw.k ; one wave each. xw bf16, q/k fp32.
__global__ void rg_qk(const unsigned short* xw, const float* q, const float* k,
                      float* qd, float* kd) {
  int lane = threadIdx.x & 63;
  int p = blockIdx.x * 4 + (threadIdx.x >> 6);
  if (p >= RG86_NR * RG86_NN) return;
  const unsigned short* xr = xw + (size_t)p * RG86_HID + lane * 4;
  float qv = 0.f, kv = 0.f;
  for (int j = 0; j < 4; j++) {
    float xv = rg_b2f(xr[j]);
    qv += xv * q[lane * 4 + j];
    kv += xv * k[lane * 4 + j];
  }
  for (int o = 32; o >= 1; o >>= 1) { qv += __shfl_xor(qv, o); kv += __shfl_xor(kv, o); }
  if (lane == 0) { qd[p] = qv; kd[p] = kv; }
}

// wave per node: leaky-relu logits, segment softmax, weighted gather. out bf16.
__global__ void rg_agg(const int* rowptr, const int* perm, const int* src,
                       const int* et, const float* qd, const float* kd,
                       const unsigned short* xw, const float* bias,
                       unsigned short* out) {
  int lane = threadIdx.x & 63;
  int node = blockIdx.x * 4 + (threadIdx.x >> 6);
  if (node >= RG86_NN) return;
  int s0 = rowptr[node], s1 = rowptr[node + 1];
  int c0 = lane * 4;
  float a0 = 0.f, a1 = 0.f, a2 = 0.f, a3 = 0.f;
  if (s1 > s0) {
    float q0 = qd[node], q1 = qd[RG86_NN + node], q2 = qd[2 * RG86_NN + node];
    float m = -1e30f;
    for (int i = s0; i < s1; i++) {
      int e = perm[i], t = et[e];
      float al = (t == 0 ? q0 : t == 1 ? q1 : q2) + kd[t * RG86_NN + src[e]];
      al = al > 0.f ? al : 0.2f * al;
      m = fmaxf(m, al);
    }
    float den = 0.f;
    for (int i = s0; i < s1; i++) {
      int e = perm[i], t = et[e];
      float al = (t == 0 ? q0 : t == 1 ? q1 : q2) + kd[t * RG86_NN + src[e]];
      al = al > 0.f ? al : 0.2f * al;
      den += __expf(al - m);
    }
    float inv = 1.f / (den + 1e-16f);
    for (int i = s0; i < s1; i++) {
      int e = perm[i], t = et[e], sv = src[e];
      float al = (t == 0 ? q0 : t == 1 ? q1 : q2) + kd[t * RG86_NN + sv];
      al = al > 0.f ? al : 0.2f * al;
      float w = __expf(al - m) * inv;
      ushort4 xr = *(const ushort4*)(xw + ((size_t)t * RG86_NN + sv) * RG86_HID + c0);
      a0 += w * rg_b2f(xr.x);
      a1 += w * rg_b2f(xr.y);
      a2 += w * rg_b2f(xr.z);
      a3 += w * rg_b2f(xr.w);
    }
  }
  unsigned short* op = out + (size_t)node * RG86_HID + c0;
  op[0] = rg_f2b(a0 + bias[c0 + 0]);
  op[1] = rg_f2b(a1 + bias[c0 + 1]);
  op[2] = rg_f2b(a2 + bias[c0 + 2]);
  op[3] = rg_f2b(a3 + bias[c0 + 3]);
}

__global__ void rg_cls(const unsigned short* h4, const float* wc, const float* bc,
                       float* out) {
  int n = blockIdx.x * 256 + threadIdx.x;
  if (n >= RG86_NN) return;
  float a0 = bc[0], a1 = bc[1];
  const unsigned short* hr = h4 + (size_t)n * RG86_OUT;
  for (int j = 0; j < RG86_OUT; j++) {
    float h = rg_b2f(hr[j]);
    a0 += h * wc[j * 2 + 0];
    a1 += h * wc[j * 2 + 1];
  }
  out[n * 2 + 0] = a0;
  out[n * 2 + 1] = a1;
}

extern "C" void kernel_launch(void* const* d_in, const int* in_sizes, int n_in,
                              void* d_out, int out_size, void* d_ws, size_t ws_size,
                              hipStream_t stream) {
  (void)in_sizes; (void)n_in; (void)out_size;
  const float* x = (const float*)d_in[0];
  const int* ei = (const int*)d_in[1];
  const int* etp = (const int*)d_in[2];
  const float* w_in = (const float*)d_in[3];
  const float* b_in = (const float*)d_in[4];
  const float* c1w = (const float*)d_in[5];
  const float* c1q = (const float*)d_in[6];
  const float* c1k = (const float*)d_in[7];
  const float* c1b = (const float*)d_in[8];
  const float* c2w = (const float*)d_in[9];
  const float* c2q = (const float*)d_in[10];
  const float* c2k = (const float*)d_in[11];
  const float* c2b = (const float*)d_in[12];
  const float* w_out = (const float*)d_in[13];
  const float* b_out = (const float*)d_in[14];
  const float* w_cls = (const float*)d_in[15];
  const float* b_cls = (const float*)d_in[16];
  const int* esrc = ei;
  const int* edst = ei + RG86_NE;

  char* base = (char*)d_ws;
  size_t off = 0;
  // xb (bf16 x) and xw (bf16 transformed feats) alias: xb dead after input GEMM
  unsigned short* xb = (unsigned short*)(base + off);
  unsigned short* xw = xb;
  off += (size_t)RG86_NN * RG86_DIN * 2;  // 76.8 MB (>= 3*NN*HID*2 = 76.8 MB)
  unsigned short* h1b = (unsigned short*)(base + off); off += (size_t)RG86_NN * RG86_HID * 2;
  unsigned short* h2b = (unsigned short*)(base + off); off += (size_t)RG86_NN * RG86_HID * 2;
  unsigned short* h4b = (unsigned short*)(base + off); off += (size_t)RG86_NN * RG86_OUT * 2;
  unsigned short* w_inT = (unsigned short*)(base + off); off += (size_t)RG86_DIN * RG86_HID * 2;
  unsigned short* c1wT = (unsigned short*)(base + off); off += (size_t)RG86_NR * RG86_HID * RG86_HID * 2;
  unsigned short* c2wT = (unsigned short*)(base + off); off += (size_t)RG86_NR * RG86_HID * RG86_HID * 2;
  unsigned short* w_outT = (unsigned short*)(base + off); off += (size_t)RG86_HID * RG86_OUT * 2;
  float* qd = (float*)(base + off); off += (size_t)RG86_NR * RG86_NN * 4;
  float* kd = (float*)(base + off); off += (size_t)RG86_NR * RG86_NN * 4;
  int* counts = (int*)(base + off); off += (size_t)RG86_NN * 4;
  int* rowptr = (int*)(base + off); off += (size_t)(RG86_NN + 4) * 4;
  int* cursor = (int*)(base + off); off += (size_t)RG86_NN * 4;
  int* perm = (int*)(base + off); off += (size_t)RG86_NE * 4;
  if (off > ws_size) return;

  int mblk = (RG86_NN + 63) / 64;          // 782 m-tiles
  int gh = mblk * (RG86_HID / 64);         // x4 n-tiles for N=256

  // casts
  rg_cast<<<(RG86_NN * RG86_DIN / 4 + 255) / 256, 256, 0, stream>>>(
      x, xb, RG86_NN * RG86_DIN);
  rg_castT<<<(RG86_DIN * RG86_HID + 255) / 256, 256, 0, stream>>>(
      w_in, w_inT, RG86_DIN, RG86_HID);
  for (int r = 0; r < RG86_NR; r++) {
    rg_castT<<<(RG86_HID * RG86_HID + 255) / 256, 256, 0, stream>>>(
        c1w + (size_t)r * RG86_HID * RG86_HID,
        c1wT + (size_t)r * RG86_HID * RG86_HID, RG86_HID, RG86_HID);
    rg_castT<<<(RG86_HID * RG86_HID + 255) / 256, 256, 0, stream>>>(
        c2w + (size_t)r * RG86_HID * RG86_HID,
        c2wT + (size_t)r * RG86_HID * RG86_HID, RG86_HID, RG86_HID);
  }
  rg_castT<<<(RG86_HID * RG86_OUT + 255) / 256, 256, 0, stream>>>(
      w_out, w_outT, RG86_HID, RG86_OUT);

  // h1 = relu(x @ w_in + b_in)
  rg_gemm_m<<<gh, 256, 0, stream>>>(xb, w_inT, b_in, h1b,
                                    RG86_NN, RG86_HID, RG86_DIN, 1, mblk);

  // CSR by dst
  hipMemsetAsync(counts, 0, (size_t)RG86_NN * 4, stream);
  rg_hist<<<(RG86_NE + 255) / 256, 256, 0, stream>>>(edst, counts);
  rg_scan<<<1, 256, 0, stream>>>(counts, rowptr, cursor, RG86_NN);
  rg_scatter<<<(RG86_NE + 255) / 256, 256, 0, stream>>>(edst, cursor, perm);

  // conv1 (xw overwrites dead xb)
  for (int r = 0; r < RG86_NR; r++)
    rg_gemm_m<<<gh, 256, 0, stream>>>(h1b, c1wT + (size_t)r * RG86_HID * RG86_HID,
                                      (const float*)0,
                                      xw + (size_t)r * RG86_NN * RG86_HID,
                                      RG86_NN, RG86_HID, RG86_HID, 0, mblk);
  rg_qk<<<(RG86_NR * RG86_NN + 3) / 4, 256, 0, stream>>>(xw, c1q, c1k, qd, kd);
  rg_agg<<<(RG86_NN + 3) / 4, 256, 0, stream>>>(rowptr, perm, esrc, etp, qd, kd,
                                                xw, c1b, h2b);

  // conv2 (h1b dead after conv1 GEMMs -> reuse as output)
  for (int r = 0; r < RG86_NR; r++)
    rg_gemm_m<<<gh, 256, 0, stream>>>(h2b, c2wT + (size_t)r * RG86_HID * RG86_HID,
                                      (const float*)0,
                                      xw + (size_t)r * RG86_NN * RG86_HID,
                                      RG86_NN, RG86_HID, RG86_HID, 0, mblk);
  rg_qk<<<(RG86_NR * RG86_NN + 3) / 4, 256, 0, stream>>>(xw, c2q, c2k, qd, kd);
  rg_agg<<<(RG86_NN + 3) / 4, 256, 0, stream>>>(rowptr, perm, esrc, etp, qd, kd,
                                                xw, c2b, h1b);

  // h4 = relu(h @ w_out + b_out)
  rg_gemm_m<<<mblk, 256, 0, stream>>>(h1b, w_outT, b_out, h4b,
                                      RG86_NN, RG86_OUT, RG86_HID, 1, mblk);

  // logits
  rg_cls<<<(RG86_NN + 255) / 256, 256, 0, stream>>>(h4b, w_cls, b_cls, (float*)d_out);
}